// Round 3
// baseline (448.589 us; speedup 1.0000x reference)
//
#include <hip/hip_runtime.h>
#include <math.h>

#define NUM_CLASSES_ 100
#define C1_ 101
#define BQ_ 3200      // B*Q = 16*200
#define QDIM_ 200

// ---------------- init: zero accumulators, set target-class map to "empty" ----------------
__global__ void init_kernel(float* acc, int* tc) {
    int i = blockIdx.x * blockDim.x + threadIdx.x;
    if (i < 4) acc[i] = 0.0f;
    if (i < BQ_) tc[i] = -1;
}

// ---------------- scatter targets with last-write-wins (numpy semantics) ----------------
__global__ void scatter_kernel(const int* __restrict__ targets,
                               const int* __restrict__ idx_b,
                               const int* __restrict__ idx_q,
                               int* tc, int M) {
    int m = blockIdx.x * blockDim.x + threadIdx.x;
    if (m < M) {
        int slot = idx_b[m] * QDIM_ + idx_q[m];
        atomicMax(&tc[slot], (m << 8) | targets[m]);
    }
}

// ---------------- weighted CE over 3200 rows x 101 classes, one wave per row ----------------
__global__ __launch_bounds__(256) void ce_kernel(const float* __restrict__ logits,
                                                 const int* __restrict__ tc,
                                                 const float* __restrict__ empty_w,
                                                 float* acc) {
    int lane = threadIdx.x & 63;
    int gw = (blockIdx.x * blockDim.x + threadIdx.x) >> 6;
    int nw = (gridDim.x * blockDim.x) >> 6;
    float lnum = 0.0f, lden = 0.0f;
    for (int row = gw; row < BQ_; row += nw) {
        const float* x = logits + (size_t)row * C1_;
        float x0 = x[lane];
        bool has2 = (lane < C1_ - 64);
        float x1 = has2 ? x[lane + 64] : -INFINITY;
        float m = fmaxf(x0, x1);
        #pragma unroll
        for (int off = 32; off; off >>= 1) m = fmaxf(m, __shfl_xor(m, off));
        float s = expf(x0 - m) + (has2 ? expf(x1 - m) : 0.0f);
        #pragma unroll
        for (int off = 32; off; off >>= 1) s += __shfl_xor(s, off);
        int packed = tc[row];
        int cls = (packed >= 0) ? (packed & 255) : NUM_CLASSES_;
        float xt = x[cls];
        float nll = -(xt - m - logf(s));
        float w = empty_w[cls];
        lnum += w * nll;
        lden += w;
    }
    if (lane == 0) { atomicAdd(&acc[0], lnum); atomicAdd(&acc[1], lden); }
}

// ---------------- per-point inverse norms: one wave per row ----------------
__global__ __launch_bounds__(256) void norm_kernel(const float* __restrict__ src,
                                                   float* __restrict__ invn, int npts) {
    int lane = threadIdx.x & 63;
    int gw = (blockIdx.x * blockDim.x + threadIdx.x) >> 6;
    int nw = (gridDim.x * blockDim.x) >> 6;
    for (int r = gw; r < npts; r += nw) {
        float s = 0.0f;
        if (lane < QDIM_ / 4) {
            float4 a = reinterpret_cast<const float4*>(src + (size_t)r * QDIM_)[lane];
            s = a.x * a.x + a.y * a.y + a.z * a.z + a.w * a.w;
        }
        #pragma unroll
        for (int off = 32; off; off >>= 1) s += __shfl_xor(s, off);
        if (lane == 0) invn[r] = 1.0f / sqrtf(s);
    }
}

// ---------------- cluster cosine loss: one wave per pair ----------------
// PRE: inv norms precomputed -> dot only + 1 butterfly. Fallback recomputes norms inline.
template <bool PRE>
__global__ __launch_bounds__(256) void pair_kernel(const float* __restrict__ src,
                                                   const int* __restrict__ pairs,
                                                   const int* __restrict__ pos,
                                                   const float* __restrict__ pw,
                                                   const float* __restrict__ invn,
                                                   float* acc, int P) {
    int lane = threadIdx.x & 63;
    int gw = (blockIdx.x * blockDim.x + threadIdx.x) >> 6;
    int nw = (gridDim.x * blockDim.x) >> 6;
    float num = 0.0f, den = 0.0f;
    #pragma unroll 2
    for (int p = gw; p < P; p += nw) {
        int2 pr = reinterpret_cast<const int2*>(pairs)[p];
        float dot = 0.0f, saa = 0.0f, sbb = 0.0f;
        if (lane < QDIM_ / 4) {
            float4 a = reinterpret_cast<const float4*>(src + (size_t)pr.x * QDIM_)[lane];
            float4 b = reinterpret_cast<const float4*>(src + (size_t)pr.y * QDIM_)[lane];
            dot = a.x * b.x + a.y * b.y + a.z * b.z + a.w * b.w;
            if (!PRE) {
                saa = a.x * a.x + a.y * a.y + a.z * a.z + a.w * a.w;
                sbb = b.x * b.x + b.y * b.y + b.z * b.z + b.w * b.w;
            }
        }
        #pragma unroll
        for (int off = 32; off; off >>= 1) {
            dot += __shfl_xor(dot, off);
            if (!PRE) {
                saa += __shfl_xor(saa, off);
                sbb += __shfl_xor(sbb, off);
            }
        }
        float cosv;
        if (PRE) {
            cosv = dot * invn[pr.x] * invn[pr.y];
        } else {
            cosv = dot / (sqrtf(saa) * sqrtf(sbb) + 1e-8f);
        }
        float per = pos[p] ? (1.0f - cosv) : fmaxf(cosv, 0.0f);
        float w = fmaxf(pw[p], 0.1f);
        num += w * per;
        den += w;
    }
    __shared__ float snum[4], sden[4];
    int wib = threadIdx.x >> 6;
    if (lane == 0) { snum[wib] = num; sden[wib] = den; }
    __syncthreads();
    if (threadIdx.x == 0) {
        atomicAdd(&acc[2], snum[0] + snum[1] + snum[2] + snum[3]);
        atomicAdd(&acc[3], sden[0] + sden[1] + sden[2] + sden[3]);
    }
}

// ---------------- combine ----------------
__global__ void final_kernel(const float* __restrict__ acc, float* out) {
    if (threadIdx.x == 0 && blockIdx.x == 0)
        out[0] = acc[0] / acc[1] + acc[2] / acc[3];
}

extern "C" void kernel_launch(void* const* d_in, const int* in_sizes, int n_in,
                              void* d_out, int out_size, void* d_ws, size_t ws_size,
                              hipStream_t stream) {
    const float* pred_logits = (const float*)d_in[0];
    const int*   targets     = (const int*)d_in[1];
    const int*   idx_b       = (const int*)d_in[2];
    const int*   idx_q       = (const int*)d_in[3];
    const float* src         = (const float*)d_in[4];
    const int*   pairs       = (const int*)d_in[5];
    const int*   pair_pos    = (const int*)d_in[6];
    const float* pair_w      = (const float*)d_in[7];
    const float* empty_w     = (const float*)d_in[8];
    float* out = (float*)d_out;

    float* acc = (float*)d_ws;                 // 4 floats
    int*   tc  = (int*)((char*)d_ws + 16);     // 3200 ints
    float* invn = (float*)((char*)d_ws + 16384);

    int M = in_sizes[1];
    int P = in_sizes[7];
    int npts = in_sizes[4] / QDIM_;

    init_kernel<<<(BQ_ + 255) / 256, 256, 0, stream>>>(acc, tc);
    scatter_kernel<<<(M + 255) / 256, 256, 0, stream>>>(targets, idx_b, idx_q, tc, M);
    ce_kernel<<<200, 256, 0, stream>>>(pred_logits, tc, empty_w, acc);

    bool pre = ws_size >= (size_t)16384 + (size_t)npts * 4;   // constant across calls
    if (pre) {
        norm_kernel<<<1024, 256, 0, stream>>>(src, invn, npts);
        pair_kernel<true><<<2048, 256, 0, stream>>>(src, pairs, pair_pos, pair_w, invn, acc, P);
    } else {
        pair_kernel<false><<<2048, 256, 0, stream>>>(src, pairs, pair_pos, pair_w, nullptr, acc, P);
    }
    final_kernel<<<1, 64, 0, stream>>>(acc, out);
}

// Round 4
// 416.104 us; speedup vs baseline: 1.0781x; 1.0781x over previous
//
#include <hip/hip_runtime.h>
#include <math.h>

#define NUM_CLASSES_ 100
#define C1_ 101
#define BQ_ 3200      // B*Q = 16*200
#define QDIM_ 200

__device__ __forceinline__ unsigned short f2bf(float f) {
    unsigned int b = __float_as_uint(f);
    unsigned int r = (b + 0x7FFFu + ((b >> 16) & 1u)) >> 16;   // RTN-even
    return (unsigned short)r;
}
__device__ __forceinline__ float bf2f(unsigned short u) {
    return __uint_as_float((unsigned int)u << 16);
}

// ---------------- init: zero accumulators, set target-class map to "empty" ----------------
__global__ void init_kernel(float* acc, int* tc) {
    int i = blockIdx.x * blockDim.x + threadIdx.x;
    if (i < 4) acc[i] = 0.0f;
    if (i < BQ_) tc[i] = -1;
}

// ---------------- scatter targets with last-write-wins (numpy semantics) ----------------
__global__ void scatter_kernel(const int* __restrict__ targets,
                               const int* __restrict__ idx_b,
                               const int* __restrict__ idx_q,
                               int* tc, int M) {
    int m = blockIdx.x * blockDim.x + threadIdx.x;
    if (m < M) {
        int slot = idx_b[m] * QDIM_ + idx_q[m];
        atomicMax(&tc[slot], (m << 8) | targets[m]);
    }
}

// ---------------- weighted CE over 3200 rows x 101 classes, one wave per row ----------------
__global__ __launch_bounds__(256) void ce_kernel(const float* __restrict__ logits,
                                                 const int* __restrict__ tc,
                                                 const float* __restrict__ empty_w,
                                                 float* acc) {
    int lane = threadIdx.x & 63;
    int gw = (blockIdx.x * blockDim.x + threadIdx.x) >> 6;
    int nw = (gridDim.x * blockDim.x) >> 6;
    float lnum = 0.0f, lden = 0.0f;
    for (int row = gw; row < BQ_; row += nw) {
        const float* x = logits + (size_t)row * C1_;
        float x0 = x[lane];
        bool has2 = (lane < C1_ - 64);
        float x1 = has2 ? x[lane + 64] : -INFINITY;
        float m = fmaxf(x0, x1);
        #pragma unroll
        for (int off = 32; off; off >>= 1) m = fmaxf(m, __shfl_xor(m, off));
        float s = expf(x0 - m) + (has2 ? expf(x1 - m) : 0.0f);
        #pragma unroll
        for (int off = 32; off; off >>= 1) s += __shfl_xor(s, off);
        int packed = tc[row];
        int cls = (packed >= 0) ? (packed & 255) : NUM_CLASSES_;
        float xt = x[cls];
        float nll = -(xt - m - logf(s));
        float w = empty_w[cls];
        lnum += w * nll;
        lden += w;
    }
    if (lane == 0) { atomicAdd(&acc[0], lnum); atomicAdd(&acc[1], lden); }
}

// ---------------- normalize rows -> bf16 unit rows (one wave per row) ----------------
__global__ __launch_bounds__(256) void normalize_kernel(const float* __restrict__ src,
                                                        unsigned short* __restrict__ nrm,
                                                        int npts) {
    int lane = threadIdx.x & 63;
    int gw = (blockIdx.x * blockDim.x + threadIdx.x) >> 6;
    int nw = (gridDim.x * blockDim.x) >> 6;
    for (int r = gw; r < npts; r += nw) {
        float4 a = make_float4(0.f, 0.f, 0.f, 0.f);
        float s = 0.0f;
        if (lane < QDIM_ / 4) {
            a = reinterpret_cast<const float4*>(src + (size_t)r * QDIM_)[lane];
            s = a.x * a.x + a.y * a.y + a.z * a.z + a.w * a.w;
        }
        #pragma unroll
        for (int off = 32; off; off >>= 1) s += __shfl_xor(s, off);
        float inv = rsqrtf(s);          // ~1 ulp; eps dropped (norm ~14 >> 1e-8)
        // one Newton step for full fp32 accuracy of rsqrt
        inv = inv * (1.5f - 0.5f * s * inv * inv);
        if (lane < QDIM_ / 4) {
            ushort4 o;
            o.x = f2bf(a.x * inv); o.y = f2bf(a.y * inv);
            o.z = f2bf(a.z * inv); o.w = f2bf(a.w * inv);
            reinterpret_cast<ushort4*>(nrm + (size_t)r * QDIM_)[lane] = o;
        }
    }
}

// ---------------- cluster cosine loss on bf16 unit rows: one wave per pair ----------------
__global__ __launch_bounds__(256) void pair_bf16_kernel(const unsigned short* __restrict__ nrm,
                                                        const int* __restrict__ pairs,
                                                        const int* __restrict__ pos,
                                                        const float* __restrict__ pw,
                                                        float* acc, int P) {
    int lane = threadIdx.x & 63;
    int gw = (blockIdx.x * blockDim.x + threadIdx.x) >> 6;
    int nw = (gridDim.x * blockDim.x) >> 6;
    float num = 0.0f, den = 0.0f;
    #pragma unroll 4
    for (int p = gw; p < P; p += nw) {
        int2 pr = reinterpret_cast<const int2*>(pairs)[p];
        float dot = 0.0f;
        if (lane < QDIM_ / 4) {    // 50 lanes x 4 bf16 = 200 elems, 8 B/lane
            ushort4 a = reinterpret_cast<const ushort4*>(nrm + (size_t)pr.x * QDIM_)[lane];
            ushort4 b = reinterpret_cast<const ushort4*>(nrm + (size_t)pr.y * QDIM_)[lane];
            dot = bf2f(a.x) * bf2f(b.x) + bf2f(a.y) * bf2f(b.y)
                + bf2f(a.z) * bf2f(b.z) + bf2f(a.w) * bf2f(b.w);
        }
        #pragma unroll
        for (int off = 32; off; off >>= 1) dot += __shfl_xor(dot, off);
        float cosv = dot;                       // rows are unit-norm
        float per = pos[p] ? (1.0f - cosv) : fmaxf(cosv, 0.0f);
        float w = fmaxf(pw[p], 0.1f);
        num += w * per;
        den += w;
    }
    __shared__ float snum[4], sden[4];
    int wib = threadIdx.x >> 6;
    if (lane == 0) { snum[wib] = num; sden[wib] = den; }
    __syncthreads();
    if (threadIdx.x == 0) {
        atomicAdd(&acc[2], snum[0] + snum[1] + snum[2] + snum[3]);
        atomicAdd(&acc[3], sden[0] + sden[1] + sden[2] + sden[3]);
    }
}

// ---------------- fp32 fallback (ws too small for bf16 table) ----------------
__global__ __launch_bounds__(256) void pair_fp32_kernel(const float* __restrict__ src,
                                                        const int* __restrict__ pairs,
                                                        const int* __restrict__ pos,
                                                        const float* __restrict__ pw,
                                                        float* acc, int P) {
    int lane = threadIdx.x & 63;
    int gw = (blockIdx.x * blockDim.x + threadIdx.x) >> 6;
    int nw = (gridDim.x * blockDim.x) >> 6;
    float num = 0.0f, den = 0.0f;
    for (int p = gw; p < P; p += nw) {
        int2 pr = reinterpret_cast<const int2*>(pairs)[p];
        float dot = 0.0f, saa = 0.0f, sbb = 0.0f;
        if (lane < QDIM_ / 4) {
            float4 a = reinterpret_cast<const float4*>(src + (size_t)pr.x * QDIM_)[lane];
            float4 b = reinterpret_cast<const float4*>(src + (size_t)pr.y * QDIM_)[lane];
            dot = a.x * b.x + a.y * b.y + a.z * b.z + a.w * b.w;
            saa = a.x * a.x + a.y * a.y + a.z * a.z + a.w * a.w;
            sbb = b.x * b.x + b.y * b.y + b.z * b.z + b.w * b.w;
        }
        #pragma unroll
        for (int off = 32; off; off >>= 1) {
            dot += __shfl_xor(dot, off);
            saa += __shfl_xor(saa, off);
            sbb += __shfl_xor(sbb, off);
        }
        float cosv = dot / (sqrtf(saa) * sqrtf(sbb) + 1e-8f);
        float per = pos[p] ? (1.0f - cosv) : fmaxf(cosv, 0.0f);
        float w = fmaxf(pw[p], 0.1f);
        num += w * per;
        den += w;
    }
    __shared__ float snum[4], sden[4];
    int wib = threadIdx.x >> 6;
    if (lane == 0) { snum[wib] = num; sden[wib] = den; }
    __syncthreads();
    if (threadIdx.x == 0) {
        atomicAdd(&acc[2], snum[0] + snum[1] + snum[2] + snum[3]);
        atomicAdd(&acc[3], sden[0] + sden[1] + sden[2] + sden[3]);
    }
}

// ---------------- combine ----------------
__global__ void final_kernel(const float* __restrict__ acc, float* out) {
    if (threadIdx.x == 0 && blockIdx.x == 0)
        out[0] = acc[0] / acc[1] + acc[2] / acc[3];
}

extern "C" void kernel_launch(void* const* d_in, const int* in_sizes, int n_in,
                              void* d_out, int out_size, void* d_ws, size_t ws_size,
                              hipStream_t stream) {
    const float* pred_logits = (const float*)d_in[0];
    const int*   targets     = (const int*)d_in[1];
    const int*   idx_b       = (const int*)d_in[2];
    const int*   idx_q       = (const int*)d_in[3];
    const float* src         = (const float*)d_in[4];
    const int*   pairs       = (const int*)d_in[5];
    const int*   pair_pos    = (const int*)d_in[6];
    const float* pair_w      = (const float*)d_in[7];
    const float* empty_w     = (const float*)d_in[8];
    float* out = (float*)d_out;

    float* acc = (float*)d_ws;                               // 4 floats
    int*   tc  = (int*)((char*)d_ws + 16);                   // 3200 ints
    unsigned short* nrm = (unsigned short*)((char*)d_ws + 16384);  // bf16 unit rows

    int M = in_sizes[1];
    int P = in_sizes[7];
    int npts = in_sizes[4] / QDIM_;

    init_kernel<<<(BQ_ + 255) / 256, 256, 0, stream>>>(acc, tc);
    scatter_kernel<<<(M + 255) / 256, 256, 0, stream>>>(targets, idx_b, idx_q, tc, M);
    ce_kernel<<<100, 256, 0, stream>>>(pred_logits, tc, empty_w, acc);

    bool bf = ws_size >= (size_t)16384 + (size_t)npts * QDIM_ * sizeof(unsigned short);
    if (bf) {
        normalize_kernel<<<2048, 256, 0, stream>>>(src, nrm, npts);
        pair_bf16_kernel<<<2048, 256, 0, stream>>>(nrm, pairs, pair_pos, pair_w, acc, P);
    } else {
        pair_fp32_kernel<<<2048, 256, 0, stream>>>(src, pairs, pair_pos, pair_w, acc, P);
    }
    final_kernel<<<1, 64, 0, stream>>>(acc, out);
}

// Round 5
// 405.653 us; speedup vs baseline: 1.1058x; 1.0258x over previous
//
#include <hip/hip_runtime.h>
#include <math.h>

#define NUM_CLASSES_ 100
#define C1_ 101
#define BQ_ 3200      // B*Q = 16*200
#define QDIM_ 200
#define ROW_DW 64     // padded row: 256 B = 64 dwords = 32 uint2

// ---------------- exact int8 dot of 8 packed bytes ----------------
static __device__ __forceinline__ int dot8i8(uint2 a, uint2 b) {
#if __has_builtin(__builtin_amdgcn_sdot4)
    int s = __builtin_amdgcn_sdot4(a.x, b.x, 0, false);
    return __builtin_amdgcn_sdot4(a.y, b.y, s, false);
#else
    int s = 0;
    #pragma unroll
    for (int k = 0; k < 4; ++k) {
        int av = (int)(a.x << (24 - 8 * k)) >> 24;
        int bv = (int)(b.x << (24 - 8 * k)) >> 24;
        int aw = (int)(a.y << (24 - 8 * k)) >> 24;
        int bw = (int)(b.y << (24 - 8 * k)) >> 24;
        s += av * bv + aw * bw;
    }
    return s;
#endif
}

// ---------------- init: zero accumulators, set target-class map to "empty" ----------------
__global__ void init_kernel(float* acc, int* tc) {
    int i = blockIdx.x * blockDim.x + threadIdx.x;
    if (i < 4) acc[i] = 0.0f;
    if (i < BQ_) tc[i] = -1;
}

// ---------------- scatter targets with last-write-wins (numpy semantics) ----------------
__global__ void scatter_kernel(const int* __restrict__ targets,
                               const int* __restrict__ idx_b,
                               const int* __restrict__ idx_q,
                               int* tc, int M) {
    int m = blockIdx.x * blockDim.x + threadIdx.x;
    if (m < M) {
        int slot = idx_b[m] * QDIM_ + idx_q[m];
        atomicMax(&tc[slot], (m << 8) | targets[m]);
    }
}

// ---------------- weighted CE over 3200 rows x 101 classes, one wave per row ----------------
__global__ __launch_bounds__(256) void ce_kernel(const float* __restrict__ logits,
                                                 const int* __restrict__ tc,
                                                 const float* __restrict__ empty_w,
                                                 float* acc) {
    int lane = threadIdx.x & 63;
    int gw = (blockIdx.x * blockDim.x + threadIdx.x) >> 6;
    int nw = (gridDim.x * blockDim.x) >> 6;
    float lnum = 0.0f, lden = 0.0f;
    for (int row = gw; row < BQ_; row += nw) {
        const float* x = logits + (size_t)row * C1_;
        float x0 = x[lane];
        bool has2 = (lane < C1_ - 64);
        float x1 = has2 ? x[lane + 64] : -INFINITY;
        float m = fmaxf(x0, x1);
        #pragma unroll
        for (int off = 32; off; off >>= 1) m = fmaxf(m, __shfl_xor(m, off));
        float s = expf(x0 - m) + (has2 ? expf(x1 - m) : 0.0f);
        #pragma unroll
        for (int off = 32; off; off >>= 1) s += __shfl_xor(s, off);
        int packed = tc[row];
        int cls = (packed >= 0) ? (packed & 255) : NUM_CLASSES_;
        float xt = x[cls];
        float nll = -(xt - m - logf(s));
        float w = empty_w[cls];
        lnum += w * nll;
        lden += w;
    }
    if (lane == 0) { atomicAdd(&acc[0], lnum); atomicAdd(&acc[1], lden); }
}

// ---------------- quantize rows -> int8 unit rows (256B padded) + invq scale ----------------
__global__ __launch_bounds__(256) void quantize_kernel(const float* __restrict__ src,
                                                       unsigned int* __restrict__ qtab,
                                                       float* __restrict__ invq, int npts) {
    int lane = threadIdx.x & 63;
    int gw = (blockIdx.x * blockDim.x + threadIdx.x) >> 6;
    int nw = (gridDim.x * blockDim.x) >> 6;
    for (int r = gw; r < npts; r += nw) {
        float4 a = make_float4(0.f, 0.f, 0.f, 0.f);
        float s = 0.0f;
        if (lane < QDIM_ / 4) {
            a = reinterpret_cast<const float4*>(src + (size_t)r * QDIM_)[lane];
            s = a.x * a.x + a.y * a.y + a.z * a.z + a.w * a.w;
        }
        #pragma unroll
        for (int off = 32; off; off >>= 1) s += __shfl_xor(s, off);
        float inv = rsqrtf(s);
        inv = inv * (1.5f - 0.5f * s * inv * inv);   // Newton -> fp32-accurate
        float sc = inv * 127.0f;
        int q0 = (int)rintf(a.x * sc);
        int q1 = (int)rintf(a.y * sc);
        int q2 = (int)rintf(a.z * sc);
        int q3 = (int)rintf(a.w * sc);
        unsigned int packed = (unsigned)(q0 & 255) | ((unsigned)(q1 & 255) << 8)
                            | ((unsigned)(q2 & 255) << 16) | ((unsigned)(q3 & 255) << 24);
        int sq = q0 * q0 + q1 * q1 + q2 * q2 + q3 * q3;   // 0 for pad lanes
        #pragma unroll
        for (int off = 32; off; off >>= 1) sq += __shfl_xor(sq, off);
        // every lane writes one dword: 50 data + 14 zero-pad = 256 B contiguous
        qtab[(size_t)r * ROW_DW + lane] = (lane < QDIM_ / 4) ? packed : 0u;
        if (lane == 0) {
            float fs = (float)sq;                 // < 2^24, exact
            float iv = rsqrtf(fs);
            iv = iv * (1.5f - 0.5f * fs * iv * iv);
            invq[r] = iv;
        }
    }
}

// ---------------- cluster cosine loss on int8 rows: one wave per pair, 4-deep pipeline ----------------
__global__ __launch_bounds__(256) void pair_i8_kernel(const uint2* __restrict__ qtab,
                                                      const int2* __restrict__ pairs2,
                                                      const int* __restrict__ pos,
                                                      const float* __restrict__ pw,
                                                      const float* __restrict__ invq,
                                                      float* acc, int P) {
    int lane = threadIdx.x & 63;
    int gw = (blockIdx.x * blockDim.x + threadIdx.x) >> 6;
    int nw = (gridDim.x * blockDim.x) >> 6;
    int chunk = (P + nw - 1) / nw;               // wave-contiguous pair range
    int pbeg = gw * chunk;
    int pend = min(P, pbeg + chunk);
    float num = 0.0f, den = 0.0f;

    int2 prA = {0, 0}, prB = {0, 0}, prC = {0, 0}, prD = {0, 0};
    uint2 vA = {0, 0}, vB = {0, 0}, vC = {0, 0}, vD = {0, 0};

    auto refill = [&](int idx, int2& pr, uint2& v) {
        if (idx < pend) {
            int i = __builtin_amdgcn_readfirstlane(idx);      // scalar path
            pr = pairs2[i];
            int row = (lane < 32) ? pr.x : pr.y;              // halves: row a / row b
            v = qtab[(size_t)row * 32 + (lane & 31)];         // 64 lanes x 8 B = both rows
        }
    };
    auto process = [&](int2 pr, uint2 v, int idx) {
        uint2 w;
        w.x = (unsigned)__shfl_xor((int)v.x, 32);             // swap halves: partner chunk
        w.y = (unsigned)__shfl_xor((int)v.y, 32);
        int d = dot8i8(v, w);
        #pragma unroll
        for (int off = 16; off; off >>= 1) d += __shfl_xor(d, off);   // 5-step, exact int
        int i = __builtin_amdgcn_readfirstlane(idx);
        float cosv = (float)d * invq[__builtin_amdgcn_readfirstlane(pr.x)]
                              * invq[__builtin_amdgcn_readfirstlane(pr.y)];
        float per = pos[i] ? (1.0f - cosv) : fmaxf(cosv, 0.0f);
        float wgt = fmaxf(pw[i], 0.1f);
        num += wgt * per;
        den += wgt;
    };

    refill(pbeg,     prA, vA);
    refill(pbeg + 1, prB, vB);
    refill(pbeg + 2, prC, vC);
    refill(pbeg + 3, prD, vD);
    for (int p = pbeg; p < pend; p += 4) {
        process(prA, vA, p);
        refill(p + 4, prA, vA);
        if (p + 1 < pend) process(prB, vB, p + 1);
        refill(p + 5, prB, vB);
        if (p + 2 < pend) process(prC, vC, p + 2);
        refill(p + 6, prC, vC);
        if (p + 3 < pend) process(prD, vD, p + 3);
        refill(p + 7, prD, vD);
    }

    __shared__ float snum[4], sden[4];
    int wib = threadIdx.x >> 6;
    if (lane == 0) { snum[wib] = num; sden[wib] = den; }
    __syncthreads();
    if (threadIdx.x == 0) {
        atomicAdd(&acc[2], snum[0] + snum[1] + snum[2] + snum[3]);
        atomicAdd(&acc[3], sden[0] + sden[1] + sden[2] + sden[3]);
    }
}

// ---------------- fp32 fallback (ws too small for int8 table) ----------------
__global__ __launch_bounds__(256) void pair_fp32_kernel(const float* __restrict__ src,
                                                        const int* __restrict__ pairs,
                                                        const int* __restrict__ pos,
                                                        const float* __restrict__ pw,
                                                        float* acc, int P) {
    int lane = threadIdx.x & 63;
    int gw = (blockIdx.x * blockDim.x + threadIdx.x) >> 6;
    int nw = (gridDim.x * blockDim.x) >> 6;
    float num = 0.0f, den = 0.0f;
    for (int p = gw; p < P; p += nw) {
        int2 pr = reinterpret_cast<const int2*>(pairs)[p];
        float dot = 0.0f, saa = 0.0f, sbb = 0.0f;
        if (lane < QDIM_ / 4) {
            float4 a = reinterpret_cast<const float4*>(src + (size_t)pr.x * QDIM_)[lane];
            float4 b = reinterpret_cast<const float4*>(src + (size_t)pr.y * QDIM_)[lane];
            dot = a.x * b.x + a.y * b.y + a.z * b.z + a.w * b.w;
            saa = a.x * a.x + a.y * a.y + a.z * a.z + a.w * a.w;
            sbb = b.x * b.x + b.y * b.y + b.z * b.z + b.w * b.w;
        }
        #pragma unroll
        for (int off = 32; off; off >>= 1) {
            dot += __shfl_xor(dot, off);
            saa += __shfl_xor(saa, off);
            sbb += __shfl_xor(sbb, off);
        }
        float cosv = dot / (sqrtf(saa) * sqrtf(sbb) + 1e-8f);
        float per = pos[p] ? (1.0f - cosv) : fmaxf(cosv, 0.0f);
        float w = fmaxf(pw[p], 0.1f);
        num += w * per;
        den += w;
    }
    __shared__ float snum[4], sden[4];
    int wib = threadIdx.x >> 6;
    if (lane == 0) { snum[wib] = num; sden[wib] = den; }
    __syncthreads();
    if (threadIdx.x == 0) {
        atomicAdd(&acc[2], snum[0] + snum[1] + snum[2] + snum[3]);
        atomicAdd(&acc[3], sden[0] + sden[1] + sden[2] + sden[3]);
    }
}

// ---------------- combine ----------------
__global__ void final_kernel(const float* __restrict__ acc, float* out) {
    if (threadIdx.x == 0 && blockIdx.x == 0)
        out[0] = acc[0] / acc[1] + acc[2] / acc[3];
}

extern "C" void kernel_launch(void* const* d_in, const int* in_sizes, int n_in,
                              void* d_out, int out_size, void* d_ws, size_t ws_size,
                              hipStream_t stream) {
    const float* pred_logits = (const float*)d_in[0];
    const int*   targets     = (const int*)d_in[1];
    const int*   idx_b       = (const int*)d_in[2];
    const int*   idx_q       = (const int*)d_in[3];
    const float* src         = (const float*)d_in[4];
    const int*   pairs       = (const int*)d_in[5];
    const int*   pair_pos    = (const int*)d_in[6];
    const float* pair_w      = (const float*)d_in[7];
    const float* empty_w     = (const float*)d_in[8];
    float* out = (float*)d_out;

    int M = in_sizes[1];
    int P = in_sizes[7];
    int npts = in_sizes[4] / QDIM_;

    float* acc = (float*)d_ws;                                   // 4 floats
    int*   tc  = (int*)((char*)d_ws + 16);                       // 3200 ints
    unsigned int* qtab = (unsigned int*)((char*)d_ws + 16384);   // npts x 256 B int8 rows
    float* invq = (float*)((char*)d_ws + 16384 + (size_t)npts * 256);

    init_kernel<<<(BQ_ + 255) / 256, 256, 0, stream>>>(acc, tc);
    scatter_kernel<<<(M + 255) / 256, 256, 0, stream>>>(targets, idx_b, idx_q, tc, M);
    ce_kernel<<<100, 256, 0, stream>>>(pred_logits, tc, empty_w, acc);

    bool i8 = ws_size >= (size_t)16384 + (size_t)npts * 256 + (size_t)npts * 4;
    if (i8) {
        quantize_kernel<<<2048, 256, 0, stream>>>(src, qtab, invq, npts);
        pair_i8_kernel<<<2048, 256, 0, stream>>>((const uint2*)qtab, (const int2*)pairs,
                                                 pair_pos, pair_w, invq, acc, P);
    } else {
        pair_fp32_kernel<<<2048, 256, 0, stream>>>(src, pairs, pair_pos, pair_w, acc, P);
    }
    final_kernel<<<1, 64, 0, stream>>>(acc, out);
}

// Round 6
// 356.313 us; speedup vs baseline: 1.2590x; 1.1385x over previous
//
#include <hip/hip_runtime.h>
#include <math.h>

#define NUM_CLASSES_ 100
#define C1_ 101
#define BQ_ 3200      // B*Q = 16*200
#define QDIM_ 200
#define ROW_DW 64     // padded row: 256 B = 64 dwords

typedef __attribute__((ext_vector_type(4))) int i32x4;

// ---------------- exact int8 dot of 8 packed bytes (quantize-side check) ----------------
static __device__ __forceinline__ int dot8i8(uint2 a, uint2 b) {
#if __has_builtin(__builtin_amdgcn_sdot4)
    int s = __builtin_amdgcn_sdot4(a.x, b.x, 0, false);
    return __builtin_amdgcn_sdot4(a.y, b.y, s, false);
#else
    int s = 0;
    #pragma unroll
    for (int k = 0; k < 4; ++k) {
        int av = (int)(a.x << (24 - 8 * k)) >> 24;
        int bv = (int)(b.x << (24 - 8 * k)) >> 24;
        int aw = (int)(a.y << (24 - 8 * k)) >> 24;
        int bw = (int)(b.y << (24 - 8 * k)) >> 24;
        s += av * bv + aw * bw;
    }
    return s;
#endif
}

// ---------------- init ----------------
__global__ void init_kernel(float* acc, int* tc) {
    int i = blockIdx.x * blockDim.x + threadIdx.x;
    if (i < 4) acc[i] = 0.0f;
    if (i < BQ_) tc[i] = -1;
}

// ---------------- scatter targets, last-write-wins ----------------
__global__ void scatter_kernel(const int* __restrict__ targets,
                               const int* __restrict__ idx_b,
                               const int* __restrict__ idx_q,
                               int* tc, int M) {
    int m = blockIdx.x * blockDim.x + threadIdx.x;
    if (m < M) {
        int slot = idx_b[m] * QDIM_ + idx_q[m];
        atomicMax(&tc[slot], (m << 8) | targets[m]);
    }
}

// ---------------- weighted CE, one wave per row ----------------
__global__ __launch_bounds__(256) void ce_kernel(const float* __restrict__ logits,
                                                 const int* __restrict__ tc,
                                                 const float* __restrict__ empty_w,
                                                 float* acc) {
    int lane = threadIdx.x & 63;
    int gw = (blockIdx.x * blockDim.x + threadIdx.x) >> 6;
    int nw = (gridDim.x * blockDim.x) >> 6;
    float lnum = 0.0f, lden = 0.0f;
    for (int row = gw; row < BQ_; row += nw) {
        const float* x = logits + (size_t)row * C1_;
        float x0 = x[lane];
        bool has2 = (lane < C1_ - 64);
        float x1 = has2 ? x[lane + 64] : -INFINITY;
        float m = fmaxf(x0, x1);
        #pragma unroll
        for (int off = 32; off; off >>= 1) m = fmaxf(m, __shfl_xor(m, off));
        float s = expf(x0 - m) + (has2 ? expf(x1 - m) : 0.0f);
        #pragma unroll
        for (int off = 32; off; off >>= 1) s += __shfl_xor(s, off);
        int packed = tc[row];
        int cls = (packed >= 0) ? (packed & 255) : NUM_CLASSES_;
        float xt = x[cls];
        float nll = -(xt - m - logf(s));
        float w = empty_w[cls];
        lnum += w * nll;
        lden += w;
    }
    if (lane == 0) { atomicAdd(&acc[0], lnum); atomicAdd(&acc[1], lden); }
}

// ---------------- quantize rows -> int8 (256B padded) + invq ----------------
__global__ __launch_bounds__(256) void quantize_kernel(const float* __restrict__ src,
                                                       unsigned int* __restrict__ qtab,
                                                       float* __restrict__ invq, int npts) {
    int lane = threadIdx.x & 63;
    int gw = (blockIdx.x * blockDim.x + threadIdx.x) >> 6;
    int nw = (gridDim.x * blockDim.x) >> 6;
    for (int r = gw; r < npts; r += nw) {
        float4 a = make_float4(0.f, 0.f, 0.f, 0.f);
        float s = 0.0f;
        if (lane < QDIM_ / 4) {
            a = reinterpret_cast<const float4*>(src + (size_t)r * QDIM_)[lane];
            s = a.x * a.x + a.y * a.y + a.z * a.z + a.w * a.w;
        }
        #pragma unroll
        for (int off = 32; off; off >>= 1) s += __shfl_xor(s, off);
        float inv = rsqrtf(s);
        inv = inv * (1.5f - 0.5f * s * inv * inv);   // Newton -> fp32-accurate
        float sc = inv * 127.0f;
        int q0 = (int)rintf(a.x * sc);
        int q1 = (int)rintf(a.y * sc);
        int q2 = (int)rintf(a.z * sc);
        int q3 = (int)rintf(a.w * sc);
        unsigned int packed = (unsigned)(q0 & 255) | ((unsigned)(q1 & 255) << 8)
                            | ((unsigned)(q2 & 255) << 16) | ((unsigned)(q3 & 255) << 24);
        int sq = q0 * q0 + q1 * q1 + q2 * q2 + q3 * q3;
        #pragma unroll
        for (int off = 32; off; off >>= 1) sq += __shfl_xor(sq, off);
        qtab[(size_t)r * ROW_DW + lane] = (lane < QDIM_ / 4) ? packed : 0u;
        if (lane == 0) {
            float fs = (float)sq;                 // < 2^24, exact
            float iv = rsqrtf(fs);
            iv = iv * (1.5f - 0.5f * fs * iv * iv);
            invq[r] = iv;
        }
    }
}

// ---------------- cluster loss via int8 MFMA: 16 pairs per chunk per wave ----------------
// Lane l: pair i = l&15 of the chunk, k-group g = l>>4.
// A-side rows = pairs[.].x, B-side = pairs[.].y. 4x mfma_i32_16x16x64_i8 over K=256.
// Diagonal of D = exact int dot of each pair (layout-permutation-proof: A and B use
// identical lane->k maps, and the diagonal is transpose-invariant).
__global__ __launch_bounds__(256) void pair_mfma_kernel(const uint4* __restrict__ qtab4,
                                                        const int2* __restrict__ pairs2,
                                                        const int* __restrict__ pos,
                                                        const float* __restrict__ pw,
                                                        const float* __restrict__ invq,
                                                        float* acc, int P) {
    int lane = threadIdx.x & 63;
    int i15 = lane & 15;
    int grp = lane >> 4;
    int gw = (blockIdx.x * blockDim.x + threadIdx.x) >> 6;
    int nw = (gridDim.x * blockDim.x) >> 6;
    int nchunks = (P + 15) / 16;

    // diag ownership: reg r with (grp*4 + r) == i15
    int myreg = i15 - (grp << 2);
    bool owns = (myreg >= 0) && (myreg < 4);

    float num = 0.0f, den = 0.0f;

    for (int c = gw; c < nchunks; c += nw) {
        int base = c * 16;
        int p = base + i15;
        int pc = min(p, P - 1);
        int2 pr = pairs2[pc];                       // 64 lanes, 16 addrs -> L1 broadcast
        const uint4* arow = qtab4 + (size_t)pr.x * 16;
        const uint4* brow = qtab4 + (size_t)pr.y * 16;

        uint4 a0 = arow[grp];        uint4 b0 = brow[grp];        // k-slice 0: bytes [g*16, g*16+16)
        uint4 a1 = arow[4 + grp];    uint4 b1 = brow[4 + grp];    // k-slice 1 (+64 B)
        uint4 a2 = arow[8 + grp];    uint4 b2 = brow[8 + grp];
        uint4 a3 = arow[12 + grp];   uint4 b3 = brow[12 + grp];

        i32x4 macc = {0, 0, 0, 0};
        macc = __builtin_amdgcn_mfma_i32_16x16x64_i8(*(i32x4*)&a0, *(i32x4*)&b0, macc, 0, 0, 0);
        macc = __builtin_amdgcn_mfma_i32_16x16x64_i8(*(i32x4*)&a1, *(i32x4*)&b1, macc, 0, 0, 0);
        macc = __builtin_amdgcn_mfma_i32_16x16x64_i8(*(i32x4*)&a2, *(i32x4*)&b2, macc, 0, 0, 0);
        macc = __builtin_amdgcn_mfma_i32_16x16x64_i8(*(i32x4*)&a3, *(i32x4*)&b3, macc, 0, 0, 0);

        if (owns && p < P) {
            int d = (myreg == 0) ? macc[0] : (myreg == 1) ? macc[1]
                  : (myreg == 2) ? macc[2] : macc[3];
            float cosv = (float)d * invq[pr.x] * invq[pr.y];
            float per = pos[p] ? (1.0f - cosv) : fmaxf(cosv, 0.0f);
            float w = fmaxf(pw[p], 0.1f);
            num += w * per;
            den += w;
        }
    }

    // one butterfly per kernel (not per pair)
    #pragma unroll
    for (int off = 32; off; off >>= 1) {
        num += __shfl_xor(num, off);
        den += __shfl_xor(den, off);
    }
    __shared__ float snum[4], sden[4];
    int wib = threadIdx.x >> 6;
    if (lane == 0) { snum[wib] = num; sden[wib] = den; }
    __syncthreads();
    if (threadIdx.x == 0) {
        atomicAdd(&acc[2], snum[0] + snum[1] + snum[2] + snum[3]);
        atomicAdd(&acc[3], sden[0] + sden[1] + sden[2] + sden[3]);
    }
}

// ---------------- fp32 fallback (ws too small for int8 table) ----------------
__global__ __launch_bounds__(256) void pair_fp32_kernel(const float* __restrict__ src,
                                                        const int* __restrict__ pairs,
                                                        const int* __restrict__ pos,
                                                        const float* __restrict__ pw,
                                                        float* acc, int P) {
    int lane = threadIdx.x & 63;
    int gw = (blockIdx.x * blockDim.x + threadIdx.x) >> 6;
    int nw = (gridDim.x * blockDim.x) >> 6;
    float num = 0.0f, den = 0.0f;
    for (int p = gw; p < P; p += nw) {
        int2 pr = reinterpret_cast<const int2*>(pairs)[p];
        float dot = 0.0f, saa = 0.0f, sbb = 0.0f;
        if (lane < QDIM_ / 4) {
            float4 a = reinterpret_cast<const float4*>(src + (size_t)pr.x * QDIM_)[lane];
            float4 b = reinterpret_cast<const float4*>(src + (size_t)pr.y * QDIM_)[lane];
            dot = a.x * b.x + a.y * b.y + a.z * b.z + a.w * b.w;
            saa = a.x * a.x + a.y * a.y + a.z * a.z + a.w * a.w;
            sbb = b.x * b.x + b.y * b.y + b.z * b.z + b.w * b.w;
        }
        #pragma unroll
        for (int off = 32; off; off >>= 1) {
            dot += __shfl_xor(dot, off);
            saa += __shfl_xor(saa, off);
            sbb += __shfl_xor(sbb, off);
        }
        float cosv = dot / (sqrtf(saa) * sqrtf(sbb) + 1e-8f);
        float per = pos[p] ? (1.0f - cosv) : fmaxf(cosv, 0.0f);
        float w = fmaxf(pw[p], 0.1f);
        num += w * per;
        den += w;
    }
    __shared__ float snum[4], sden[4];
    int wib = threadIdx.x >> 6;
    if (lane == 0) { snum[wib] = num; sden[wib] = den; }
    __syncthreads();
    if (threadIdx.x == 0) {
        atomicAdd(&acc[2], snum[0] + snum[1] + snum[2] + snum[3]);
        atomicAdd(&acc[3], sden[0] + sden[1] + sden[2] + sden[3]);
    }
}

// ---------------- combine ----------------
__global__ void final_kernel(const float* __restrict__ acc, float* out) {
    if (threadIdx.x == 0 && blockIdx.x == 0)
        out[0] = acc[0] / acc[1] + acc[2] / acc[3];
}

extern "C" void kernel_launch(void* const* d_in, const int* in_sizes, int n_in,
                              void* d_out, int out_size, void* d_ws, size_t ws_size,
                              hipStream_t stream) {
    const float* pred_logits = (const float*)d_in[0];
    const int*   targets     = (const int*)d_in[1];
    const int*   idx_b       = (const int*)d_in[2];
    const int*   idx_q       = (const int*)d_in[3];
    const float* src         = (const float*)d_in[4];
    const int*   pairs       = (const int*)d_in[5];
    const int*   pair_pos    = (const int*)d_in[6];
    const float* pair_w      = (const float*)d_in[7];
    const float* empty_w     = (const float*)d_in[8];
    float* out = (float*)d_out;

    int M = in_sizes[1];
    int P = in_sizes[7];
    int npts = in_sizes[4] / QDIM_;

    float* acc = (float*)d_ws;                                   // 4 floats
    int*   tc  = (int*)((char*)d_ws + 16);                       // 3200 ints
    unsigned int* qtab = (unsigned int*)((char*)d_ws + 16384);   // npts x 256 B int8 rows
    float* invq = (float*)((char*)d_ws + 16384 + (size_t)npts * 256);

    init_kernel<<<(BQ_ + 255) / 256, 256, 0, stream>>>(acc, tc);
    scatter_kernel<<<(M + 255) / 256, 256, 0, stream>>>(targets, idx_b, idx_q, tc, M);
    ce_kernel<<<200, 256, 0, stream>>>(pred_logits, tc, empty_w, acc);

    bool i8 = ws_size >= (size_t)16384 + (size_t)npts * 256 + (size_t)npts * 4;
    if (i8) {
        quantize_kernel<<<2048, 256, 0, stream>>>(src, qtab, invq, npts);
        pair_mfma_kernel<<<2048, 256, 0, stream>>>((const uint4*)qtab, (const int2*)pairs,
                                                   pair_pos, pair_w, invq, acc, P);
    } else {
        pair_fp32_kernel<<<2048, 256, 0, stream>>>(src, pairs, pair_pos, pair_w, acc, P);
    }
    final_kernel<<<1, 64, 0, stream>>>(acc, out);
}

// Round 7
// 349.671 us; speedup vs baseline: 1.2829x; 1.0190x over previous
//
#include <hip/hip_runtime.h>
#include <math.h>

#define NUM_CLASSES_ 100
#define C1_ 101
#define BQ_ 3200      // B*Q = 16*200
#define QDIM_ 200
#define ROW_DW 64     // padded row: 256 B = 64 dwords

typedef __attribute__((ext_vector_type(4))) int i32x4;

// ---------------- init ----------------
__global__ void init_kernel(float* acc, int* tc) {
    int i = blockIdx.x * blockDim.x + threadIdx.x;
    if (i < 4) acc[i] = 0.0f;
    if (i < BQ_) tc[i] = -1;
}

// ---------------- scatter targets, last-write-wins ----------------
__global__ void scatter_kernel(const int* __restrict__ targets,
                               const int* __restrict__ idx_b,
                               const int* __restrict__ idx_q,
                               int* tc, int M) {
    int m = blockIdx.x * blockDim.x + threadIdx.x;
    if (m < M) {
        int slot = idx_b[m] * QDIM_ + idx_q[m];
        atomicMax(&tc[slot], (m << 8) | targets[m]);
    }
}

// ---------------- weighted CE, one wave per row ----------------
__global__ __launch_bounds__(256) void ce_kernel(const float* __restrict__ logits,
                                                 const int* __restrict__ tc,
                                                 const float* __restrict__ empty_w,
                                                 float* acc) {
    int lane = threadIdx.x & 63;
    int gw = (blockIdx.x * blockDim.x + threadIdx.x) >> 6;
    int nw = (gridDim.x * blockDim.x) >> 6;
    float lnum = 0.0f, lden = 0.0f;
    for (int row = gw; row < BQ_; row += nw) {
        const float* x = logits + (size_t)row * C1_;
        float x0 = x[lane];
        bool has2 = (lane < C1_ - 64);
        float x1 = has2 ? x[lane + 64] : -INFINITY;
        float m = fmaxf(x0, x1);
        #pragma unroll
        for (int off = 32; off; off >>= 1) m = fmaxf(m, __shfl_xor(m, off));
        float s = expf(x0 - m) + (has2 ? expf(x1 - m) : 0.0f);
        #pragma unroll
        for (int off = 32; off; off >>= 1) s += __shfl_xor(s, off);
        int packed = tc[row];
        int cls = (packed >= 0) ? (packed & 255) : NUM_CLASSES_;
        float xt = x[cls];
        float nll = -(xt - m - logf(s));
        float w = empty_w[cls];
        lnum += w * nll;
        lden += w;
    }
    if (lane == 0) { atomicAdd(&acc[0], lnum); atomicAdd(&acc[1], lden); }
}

// ---------------- quantize rows -> int8 (256B padded) + invq ----------------
__global__ __launch_bounds__(256) void quantize_kernel(const float* __restrict__ src,
                                                       unsigned int* __restrict__ qtab,
                                                       float* __restrict__ invq, int npts) {
    int lane = threadIdx.x & 63;
    int gw = (blockIdx.x * blockDim.x + threadIdx.x) >> 6;
    int nw = (gridDim.x * blockDim.x) >> 6;
    for (int r = gw; r < npts; r += nw) {
        float4 a = make_float4(0.f, 0.f, 0.f, 0.f);
        float s = 0.0f;
        if (lane < QDIM_ / 4) {
            a = reinterpret_cast<const float4*>(src + (size_t)r * QDIM_)[lane];
            s = a.x * a.x + a.y * a.y + a.z * a.z + a.w * a.w;
        }
        #pragma unroll
        for (int off = 32; off; off >>= 1) s += __shfl_xor(s, off);
        float inv = rsqrtf(s);
        inv = inv * (1.5f - 0.5f * s * inv * inv);   // Newton -> fp32-accurate
        float sc = inv * 127.0f;
        int q0 = (int)rintf(a.x * sc);
        int q1 = (int)rintf(a.y * sc);
        int q2 = (int)rintf(a.z * sc);
        int q3 = (int)rintf(a.w * sc);
        unsigned int packed = (unsigned)(q0 & 255) | ((unsigned)(q1 & 255) << 8)
                            | ((unsigned)(q2 & 255) << 16) | ((unsigned)(q3 & 255) << 24);
        int sq = q0 * q0 + q1 * q1 + q2 * q2 + q3 * q3;
        #pragma unroll
        for (int off = 32; off; off >>= 1) sq += __shfl_xor(sq, off);
        qtab[(size_t)r * ROW_DW + lane] = (lane < QDIM_ / 4) ? packed : 0u;
        if (lane == 0) {
            float fs = (float)sq;                 // < 2^24, exact
            float iv = rsqrtf(fs);
            iv = iv * (1.5f - 0.5f * fs * iv * iv);
            invq[r] = iv;
        }
    }
}

// ---------------- cluster loss via int8 MFMA, depth-2 chunk pipeline ----------------
// Lane l: pair i = l&15, k-group g = l>>4. 4x mfma_i32_16x16x64_i8 over K=256.
// Diagonal of D = exact int dot per pair (A/B share the lane->k map; diagonal is
// transpose-invariant, so the result doesn't depend on undocumented fragment layout).
__global__ __launch_bounds__(256) void pair_mfma_kernel(const uint4* __restrict__ qtab4,
                                                        const int2* __restrict__ pairs2,
                                                        const int* __restrict__ pos,
                                                        const float* __restrict__ pw,
                                                        const float* __restrict__ invq,
                                                        float* acc, int P) {
    int lane = threadIdx.x & 63;
    int i15 = lane & 15;
    int grp = lane >> 4;
    int gw = (blockIdx.x * blockDim.x + threadIdx.x) >> 6;
    int nw = (gridDim.x * blockDim.x) >> 6;
    int nchunks = (P + 15) / 16;

    int myreg = i15 - (grp << 2);                 // diag ownership
    bool owns = (myreg >= 0) && (myreg < 4);

    float num = 0.0f, den = 0.0f;

    // --- two named pipeline stages (rule #20: no runtime-indexed arrays) ---
    int pA; int2 prA; uint4 a0A, a1A, a2A, a3A, b0A, b1A, b2A, b3A;
    int posA; float pwA, iqA;
    int pB; int2 prB; uint4 a0B, a1B, a2B, a3B, b0B, b1B, b2B, b3B;
    int posB; float pwB, iqB;

    auto loadA = [&](int c) {
        pA = c * 16 + i15;
        int pc = min(pA, P - 1);
        prA = pairs2[pc];
        const uint4* ar = qtab4 + (size_t)prA.x * 16;
        const uint4* br = qtab4 + (size_t)prA.y * 16;
        a0A = ar[grp]; a1A = ar[4 + grp]; a2A = ar[8 + grp]; a3A = ar[12 + grp];
        b0A = br[grp]; b1A = br[4 + grp]; b2A = br[8 + grp]; b3A = br[12 + grp];
        posA = pos[pc]; pwA = pw[pc];
        iqA = invq[prA.x] * invq[prA.y];
    };
    auto loadB = [&](int c) {
        pB = c * 16 + i15;
        int pc = min(pB, P - 1);
        prB = pairs2[pc];
        const uint4* ar = qtab4 + (size_t)prB.x * 16;
        const uint4* br = qtab4 + (size_t)prB.y * 16;
        a0B = ar[grp]; a1B = ar[4 + grp]; a2B = ar[8 + grp]; a3B = ar[12 + grp];
        b0B = br[grp]; b1B = br[4 + grp]; b2B = br[8 + grp]; b3B = br[12 + grp];
        posB = pos[pc]; pwB = pw[pc];
        iqB = invq[prB.x] * invq[prB.y];
    };
    auto procA = [&]() {
        i32x4 macc = {0, 0, 0, 0};
        macc = __builtin_amdgcn_mfma_i32_16x16x64_i8(*(i32x4*)&a0A, *(i32x4*)&b0A, macc, 0, 0, 0);
        macc = __builtin_amdgcn_mfma_i32_16x16x64_i8(*(i32x4*)&a1A, *(i32x4*)&b1A, macc, 0, 0, 0);
        macc = __builtin_amdgcn_mfma_i32_16x16x64_i8(*(i32x4*)&a2A, *(i32x4*)&b2A, macc, 0, 0, 0);
        macc = __builtin_amdgcn_mfma_i32_16x16x64_i8(*(i32x4*)&a3A, *(i32x4*)&b3A, macc, 0, 0, 0);
        if (owns && pA < P) {
            int d = (myreg == 0) ? macc[0] : (myreg == 1) ? macc[1]
                  : (myreg == 2) ? macc[2] : macc[3];
            float cosv = (float)d * iqA;
            float per = posA ? (1.0f - cosv) : fmaxf(cosv, 0.0f);
            float w = fmaxf(pwA, 0.1f);
            num += w * per;
            den += w;
        }
    };
    auto procB = [&]() {
        i32x4 macc = {0, 0, 0, 0};
        macc = __builtin_amdgcn_mfma_i32_16x16x64_i8(*(i32x4*)&a0B, *(i32x4*)&b0B, macc, 0, 0, 0);
        macc = __builtin_amdgcn_mfma_i32_16x16x64_i8(*(i32x4*)&a1B, *(i32x4*)&b1B, macc, 0, 0, 0);
        macc = __builtin_amdgcn_mfma_i32_16x16x64_i8(*(i32x4*)&a2B, *(i32x4*)&b2B, macc, 0, 0, 0);
        macc = __builtin_amdgcn_mfma_i32_16x16x64_i8(*(i32x4*)&a3B, *(i32x4*)&b3B, macc, 0, 0, 0);
        if (owns && pB < P) {
            int d = (myreg == 0) ? macc[0] : (myreg == 1) ? macc[1]
                  : (myreg == 2) ? macc[2] : macc[3];
            float cosv = (float)d * iqB;
            float per = posB ? (1.0f - cosv) : fmaxf(cosv, 0.0f);
            float w = fmaxf(pwB, 0.1f);
            num += w * per;
            den += w;
        }
    };

    if (gw < nchunks) {
        loadA(gw);
        int c = gw;
        for (;;) {
            int cB = c + nw;
            bool hasB = (cB < nchunks);
            if (hasB) loadB(cB);
            procA();
            if (!hasB) break;
            int cA = cB + nw;
            bool hasA = (cA < nchunks);
            if (hasA) loadA(cA);
            procB();
            if (!hasA) break;
            c = cA;
        }
    }

    #pragma unroll
    for (int off = 32; off; off >>= 1) {
        num += __shfl_xor(num, off);
        den += __shfl_xor(den, off);
    }
    __shared__ float snum[4], sden[4];
    int wib = threadIdx.x >> 6;
    if (lane == 0) { snum[wib] = num; sden[wib] = den; }
    __syncthreads();
    if (threadIdx.x == 0) {
        atomicAdd(&acc[2], snum[0] + snum[1] + snum[2] + snum[3]);
        atomicAdd(&acc[3], sden[0] + sden[1] + sden[2] + sden[3]);
    }
}

// ---------------- fp32 fallback (ws too small for int8 table) ----------------
__global__ __launch_bounds__(256) void pair_fp32_kernel(const float* __restrict__ src,
                                                        const int* __restrict__ pairs,
                                                        const int* __restrict__ pos,
                                                        const float* __restrict__ pw,
                                                        float* acc, int P) {
    int lane = threadIdx.x & 63;
    int gw = (blockIdx.x * blockDim.x + threadIdx.x) >> 6;
    int nw = (gridDim.x * blockDim.x) >> 6;
    float num = 0.0f, den = 0.0f;
    for (int p = gw; p < P; p += nw) {
        int2 pr = reinterpret_cast<const int2*>(pairs)[p];
        float dot = 0.0f, saa = 0.0f, sbb = 0.0f;
        if (lane < QDIM_ / 4) {
            float4 a = reinterpret_cast<const float4*>(src + (size_t)pr.x * QDIM_)[lane];
            float4 b = reinterpret_cast<const float4*>(src + (size_t)pr.y * QDIM_)[lane];
            dot = a.x * b.x + a.y * b.y + a.z * b.z + a.w * b.w;
            saa = a.x * a.x + a.y * a.y + a.z * a.z + a.w * a.w;
            sbb = b.x * b.x + b.y * b.y + b.z * b.z + b.w * b.w;
        }
        #pragma unroll
        for (int off = 32; off; off >>= 1) {
            dot += __shfl_xor(dot, off);
            saa += __shfl_xor(saa, off);
            sbb += __shfl_xor(sbb, off);
        }
        float cosv = dot / (sqrtf(saa) * sqrtf(sbb) + 1e-8f);
        float per = pos[p] ? (1.0f - cosv) : fmaxf(cosv, 0.0f);
        float w = fmaxf(pw[p], 0.1f);
        num += w * per;
        den += w;
    }
    __shared__ float snum[4], sden[4];
    int wib = threadIdx.x >> 6;
    if (lane == 0) { snum[wib] = num; sden[wib] = den; }
    __syncthreads();
    if (threadIdx.x == 0) {
        atomicAdd(&acc[2], snum[0] + snum[1] + snum[2] + snum[3]);
        atomicAdd(&acc[3], sden[0] + sden[1] + sden[2] + sden[3]);
    }
}

// ---------------- combine ----------------
__global__ void final_kernel(const float* __restrict__ acc, float* out) {
    if (threadIdx.x == 0 && blockIdx.x == 0)
        out[0] = acc[0] / acc[1] + acc[2] / acc[3];
}

extern "C" void kernel_launch(void* const* d_in, const int* in_sizes, int n_in,
                              void* d_out, int out_size, void* d_ws, size_t ws_size,
                              hipStream_t stream) {
    const float* pred_logits = (const float*)d_in[0];
    const int*   targets     = (const int*)d_in[1];
    const int*   idx_b       = (const int*)d_in[2];
    const int*   idx_q       = (const int*)d_in[3];
    const float* src         = (const float*)d_in[4];
    const int*   pairs       = (const int*)d_in[5];
    const int*   pair_pos    = (const int*)d_in[6];
    const float* pair_w      = (const float*)d_in[7];
    const float* empty_w     = (const float*)d_in[8];
    float* out = (float*)d_out;

    int M = in_sizes[1];
    int P = in_sizes[7];
    int npts = in_sizes[4] / QDIM_;

    float* acc = (float*)d_ws;                                   // 4 floats
    int*   tc  = (int*)((char*)d_ws + 16);                       // 3200 ints
    unsigned int* qtab = (unsigned int*)((char*)d_ws + 16384);   // npts x 256 B int8 rows
    float* invq = (float*)((char*)d_ws + 16384 + (size_t)npts * 256);

    init_kernel<<<(BQ_ + 255) / 256, 256, 0, stream>>>(acc, tc);
    scatter_kernel<<<(M + 255) / 256, 256, 0, stream>>>(targets, idx_b, idx_q, tc, M);
    ce_kernel<<<200, 256, 0, stream>>>(pred_logits, tc, empty_w, acc);

    bool i8 = ws_size >= (size_t)16384 + (size_t)npts * 256 + (size_t)npts * 4;
    if (i8) {
        quantize_kernel<<<2048, 256, 0, stream>>>(src, qtab, invq, npts);
        pair_mfma_kernel<<<2048, 256, 0, stream>>>((const uint4*)qtab, (const int2*)pairs,
                                                   pair_pos, pair_w, invq, acc, P);
    } else {
        pair_fp32_kernel<<<2048, 256, 0, stream>>>(src, pairs, pair_pos, pair_w, acc, P);
    }
    final_kernel<<<1, 64, 0, stream>>>(acc, out);
}